// Round 5
// baseline (323.703 us; speedup 1.0000x reference)
//
#include <hip/hip_runtime.h>
#include <hip/hip_bf16.h>

#define LL   2048
#define DIM  512
#define HD   64
#define BHN  16      // batch * NH
#define NC   128     // chunks along L
#define CH   16      // chunk length = LL/NC
#define EPSF 1e-8f

typedef __attribute__((ext_vector_type(8))) short bf16x8;   // 8 bf16 = 4 VGPRs
typedef __attribute__((ext_vector_type(4))) float f32x4;    // MFMA C/D + native 16B vector

__device__ __forceinline__ void nt_store(float* p, float v) {
    __builtin_nontemporal_store(v, p);
}
__device__ __forceinline__ void nt_store4(f32x4* p, f32x4 v) {
    __builtin_nontemporal_store(v, p);
}

// ---------------- Kernel 1: per-chunk product of A (A_0 := 1) ----------------
__global__ __launch_bounds__(64) void chunkprod_kernel(const float* __restrict__ S,
                                                       float* __restrict__ U) {
    int c = blockIdx.x, bh = blockIdx.y;
    int b = bh >> 3, h = bh & 7;
    int d = threadIdx.x;
    int l0 = c * CH;
    size_t base = ((size_t)b * LL + l0) * DIM + h * HD + d;
    float p = 1.0f;
    #pragma unroll
    for (int l = 0; l < CH; ++l) {
        float a = S[base + (size_t)l * DIM];
        if (l0 + l >= 1) p *= a;   // position 0's A is replaced by 1
    }
    U[((size_t)bh * NC + c) * HD + d] = p;
}

// --- Kernel 2: fused rescan: X = bf16(C*P), Y = bf16(B/D), diag = C.B --------
// Chunk prefix is rebuilt from U in-block (U = 512 KB, L2-hot); the diag
// reduction runs as 16 independent shfl trees AFTER the serial p-loop so it
// never extends the p dependency chain.
__global__ __launch_bounds__(64) void apply_kernel(const float* __restrict__ Bg,
                                                   const float* __restrict__ Cg,
                                                   const float* __restrict__ S,
                                                   const float* __restrict__ U,
                                                   __hip_bfloat16* __restrict__ X,
                                                   __hip_bfloat16* __restrict__ Y,
                                                   float* __restrict__ diag) {
    int c = blockIdx.x, bh = blockIdx.y;
    int b = bh >> 3, h = bh & 7;
    int d = threadIdx.x;
    int l0 = c * CH;

    // P[l0] = prod over chunks cc < c (coalesced 256B loads, independent; then VALU chain)
    float p = 1.0f;
    for (int cc = 0; cc < c; ++cc)
        p *= U[((size_t)bh * NC + cc) * HD + d];

    size_t gbase = ((size_t)b * LL + l0) * DIM + h * HD + d;
    float tv[CH];
    #pragma unroll
    for (int l = 0; l < CH; ++l) {
        int gl = l0 + l;
        size_t gi = gbase + (size_t)l * DIM;
        float a = S[gi], bv = Bg[gi], cv = Cg[gi];
        float Dv = (gl == 0) ? 1.0f : (p + EPSF);
        size_t o = ((size_t)bh * LL + gl) * HD + d;
        X[o] = __float2bfloat16(cv * p);    // mirror reference: C*P and B/D separate
        Y[o] = __float2bfloat16(bv / Dv);
        tv[l] = cv * bv;                    // diag partial (fp32 exact)
        if (gl >= 1) p *= a;                // advance to P[gl+1]
    }
    // 16 independent 6-level reduces — ILP hides shuffle latency
    #pragma unroll
    for (int l = 0; l < CH; ++l) {
        float s = tv[l];
        #pragma unroll
        for (int off = 1; off < 64; off <<= 1) s += __shfl_xor(s, off);
        tv[l] = s;
    }
    if (d == 0) {
        float* dp = diag + (size_t)bh * LL + l0;
        #pragma unroll
        for (int q4 = 0; q4 < CH / 4; ++q4) {
            f32x4 v = {tv[4 * q4], tv[4 * q4 + 1], tv[4 * q4 + 2], tv[4 * q4 + 3]};
            *((f32x4*)dp + q4) = v;          // plain store: gemm reads this soon (keep in L2)
        }
    }
}

// ------------- Kernel 3: MFMA bf16 GEMM  T = X Y^T (lower), diag, 0 ----------
// 128x128 tile, K=64 one-shot. LDS 2x16KB, 16B-chunk XOR swizzle (<=2-way, free).
// 4 waves, each 64x64 via 4x4 tiles of mfma_f32_16x16x32_bf16.
__global__ __launch_bounds__(256) void gemm_kernel(const __hip_bfloat16* __restrict__ X,
                                                   const __hip_bfloat16* __restrict__ Y,
                                                   const float* __restrict__ diag,
                                                   float* __restrict__ out) {
    int tj = blockIdx.x, ti = blockIdx.y, bh = blockIdx.z;
    size_t obase = (size_t)bh * LL * LL;
    int i0 = ti * 128, j0 = tj * 128;
    int t = threadIdx.x;

    if (tj > ti) {   // fully strict-upper tile: zero-fill only (uniform branch)
        f32x4 z = {0.f, 0.f, 0.f, 0.f};
        int col4 = t & 31, row0 = t >> 5;
        float* ob = out + obase + (size_t)i0 * LL + j0;
        #pragma unroll
        for (int r = 0; r < 16; ++r)
            nt_store4((f32x4*)(ob + (size_t)(row0 + 8 * r) * LL) + col4, z);
        return;
    }

    __shared__ short Xs[128 * 64];   // bf16 bits, row-major 64/row, swizzled chunks
    __shared__ short Ys[128 * 64];

    // ---- stage 128 rows x 64 bf16 per operand (16B/lane x 4 passes) ----
    {
        const f32x4* Xg4 = (const f32x4*)(X + ((size_t)bh * LL + i0) * HD);
        const f32x4* Yg4 = (const f32x4*)(Y + ((size_t)bh * LL + j0) * HD);
        int chunk = t & 7, r0 = t >> 3;    // chunk: 16B unit within row; r0: 0..31
        int sc = (chunk ^ (r0 & 7)) * 8;   // row&7 == r0&7 (rows step by 32)
        #pragma unroll
        for (int p = 0; p < 4; ++p) {
            int row = r0 + 32 * p;
            f32x4 vx = Xg4[row * 8 + chunk];
            f32x4 vy = Yg4[row * 8 + chunk];
            *(f32x4*)&Xs[row * 64 + sc] = vx;
            *(f32x4*)&Ys[row * 64 + sc] = vy;
        }
    }
    __syncthreads();

    // ---- compute: wave (wi,wj) owns 64x64; 4x4 tiles of 16x16, K=64 ----
    int lane = t & 63, wv = t >> 6;
    int wi = wv >> 1, wj = wv & 1;
    int l15 = lane & 15, q = lane >> 4;

    f32x4 acc[4][4] = {};
    #pragma unroll
    for (int kc = 0; kc < 2; ++kc) {
        bf16x8 af[4], bf[4];
        #pragma unroll
        for (int mt = 0; mt < 4; ++mt) {
            int row = 64 * wi + 16 * mt + l15;           // A[m][k]: m=lane&15
            int sc = ((4 * kc + q) ^ (row & 7)) * 8;     // k-chunk = 4*kc + quad
            af[mt] = *(const bf16x8*)&Xs[row * 64 + sc];
        }
        #pragma unroll
        for (int nt = 0; nt < 4; ++nt) {
            int row = 64 * wj + 16 * nt + l15;           // B[k][n]: n=lane&15
            int sc = ((4 * kc + q) ^ (row & 7)) * 8;
            bf[nt] = *(const bf16x8*)&Ys[row * 64 + sc];
        }
        #pragma unroll
        for (int mt = 0; mt < 4; ++mt)
            #pragma unroll
            for (int nt = 0; nt < 4; ++nt)
                acc[mt][nt] = __builtin_amdgcn_mfma_f32_16x16x32_bf16(
                    af[mt], bf[nt], acc[mt][nt], 0, 0, 0);
    }

    // ---- epilogue: C/D layout col=lane&15, row=quad*4+reg ----
    int i_base = i0 + 64 * wi, j_base = j0 + 64 * wj;
    if (tj < ti) {   // fully strict-lower: store everything
        #pragma unroll
        for (int mt = 0; mt < 4; ++mt)
            #pragma unroll
            for (int reg = 0; reg < 4; ++reg) {
                int gi = i_base + 16 * mt + 4 * q + reg;
                float* ob = out + obase + (size_t)gi * LL + j_base;
                #pragma unroll
                for (int nt = 0; nt < 4; ++nt)
                    nt_store(ob + 16 * nt + l15, acc[mt][nt][reg]);
            }
    } else {         // diagonal tile: mask j>i to 0, j==i to diag
        #pragma unroll
        for (int mt = 0; mt < 4; ++mt)
            #pragma unroll
            for (int reg = 0; reg < 4; ++reg) {
                int gi = i_base + 16 * mt + 4 * q + reg;
                float dv = diag[(size_t)bh * LL + gi];
                float* ob = out + obase + (size_t)gi * LL + j_base;
                #pragma unroll
                for (int nt = 0; nt < 4; ++nt) {
                    int gj = j_base + 16 * nt + l15;
                    float v = acc[mt][nt][reg];
                    nt_store(ob + 16 * nt + l15,
                             (gj < gi) ? v : ((gj == gi) ? dv : 0.f));
                }
            }
    }
}

extern "C" void kernel_launch(void* const* d_in, const int* in_sizes, int n_in,
                              void* d_out, int out_size, void* d_ws, size_t ws_size,
                              hipStream_t stream) {
    const float* Bg = (const float*)d_in[0];
    const float* Cg = (const float*)d_in[1];
    const float* S  = (const float*)d_in[2];
    float* out = (float*)d_out;

    char* ws = (char*)d_ws;
    size_t xy_bytes = (size_t)BHN * LL * HD * sizeof(__hip_bfloat16);  // 4 MB each
    __hip_bfloat16* X = (__hip_bfloat16*)(ws);
    __hip_bfloat16* Y = (__hip_bfloat16*)(ws + xy_bytes);
    float* diag = (float*)(ws + 2 * xy_bytes);
    float* U    = (float*)(ws + 2 * xy_bytes + (size_t)BHN * LL * sizeof(float));

    chunkprod_kernel<<<dim3(NC, BHN), 64, 0, stream>>>(S, U);
    apply_kernel<<<dim3(NC, BHN), 64, 0, stream>>>(Bg, Cg, S, U, X, Y, diag);
    gemm_kernel<<<dim3(16, 16, BHN), 256, 0, stream>>>(X, Y, diag, out);
}

// Round 6
// 299.457 us; speedup vs baseline: 1.0810x; 1.0810x over previous
//
#include <hip/hip_runtime.h>
#include <hip/hip_bf16.h>

#define LL   2048
#define DIM  512
#define HD   64
#define BHN  16      // batch * NH
#define NC   128     // chunks along L
#define CH   16      // chunk length = LL/NC
#define GC   8       // chunks per scan-group (NC / 16 groups)
#define EPSF 1e-8f

typedef __attribute__((ext_vector_type(8))) short bf16x8;   // 8 bf16 = 4 VGPRs
typedef __attribute__((ext_vector_type(4))) float f32x4;    // MFMA C/D + native 16B vector

__device__ __forceinline__ void nt_store(float* p, float v) {
    __builtin_nontemporal_store(v, p);
}
__device__ __forceinline__ void nt_store4(f32x4* p, f32x4 v) {
    __builtin_nontemporal_store(v, p);
}

// ---------------- Kernel 1: per-chunk product of A (A_0 := 1) ----------------
__global__ __launch_bounds__(64) void chunkprod_kernel(const float* __restrict__ S,
                                                       float* __restrict__ U) {
    int c = blockIdx.x, bh = blockIdx.y;
    int b = bh >> 3, h = bh & 7;
    int d = threadIdx.x;
    int l0 = c * CH;
    size_t base = ((size_t)b * LL + l0) * DIM + h * HD + d;
    float p = 1.0f;
    #pragma unroll
    for (int l = 0; l < CH; ++l) {
        float a = S[base + (size_t)l * DIM];
        if (l0 + l >= 1) p *= a;   // position 0's A is replaced by 1
    }
    U[((size_t)bh * NC + c) * HD + d] = p;
}

// ------- Kernel 2: parallel exclusive scan of chunk products (per bh) --------
// 1024 threads: group g = t>>6 owns GC=8 chunks for channel d = t&63.
__global__ __launch_bounds__(1024) void chunkscan_kernel(const float* __restrict__ U,
                                                         float* __restrict__ St) {
    int bh = blockIdx.x;
    int t = threadIdx.x;
    int g = t >> 6, d = t & 63;
    int c0 = g * GC;
    float u[GC];
    float prod = 1.0f;
    #pragma unroll
    for (int k = 0; k < GC; ++k) {
        u[k] = U[((size_t)bh * NC + c0 + k) * HD + d];
        prod *= u[k];
    }
    __shared__ float Ls[16][64];
    Ls[g][d] = prod;
    __syncthreads();
    float run = 1.0f;
    for (int gg = 0; gg < g; ++gg) run *= Ls[gg][d];   // g uniform per wave
    #pragma unroll
    for (int k = 0; k < GC; ++k) {
        St[((size_t)bh * NC + c0 + k) * HD + d] = run;
        run *= u[k];
    }
}

// -- Kernel 3: rescan chunk: X = bf16(C*P), Y = bf16(B/D), diag = C.B (fused) -
// Prefix comes from St (single load). Diag partials are stashed per-iteration
// and reduced AFTER the serial p-loop as 16 independent shfl trees (ILP hides
// shuffle latency; nothing enters the p dependency chain).
__global__ __launch_bounds__(64) void apply_kernel(const float* __restrict__ Bg,
                                                   const float* __restrict__ Cg,
                                                   const float* __restrict__ S,
                                                   const float* __restrict__ St,
                                                   __hip_bfloat16* __restrict__ X,
                                                   __hip_bfloat16* __restrict__ Y,
                                                   float* __restrict__ diag) {
    int c = blockIdx.x, bh = blockIdx.y;
    int b = bh >> 3, h = bh & 7;
    int d = threadIdx.x;
    int l0 = c * CH;
    size_t gbase = ((size_t)b * LL + l0) * DIM + h * HD + d;
    float p = St[((size_t)bh * NC + c) * HD + d];   // P[l0] = prod_{k=1..l0-1} A_k
    float tv[CH];
    #pragma unroll
    for (int l = 0; l < CH; ++l) {
        int gl = l0 + l;
        size_t gi = gbase + (size_t)l * DIM;
        float a = S[gi], bv = Bg[gi], cv = Cg[gi];
        float Dv = (gl == 0) ? 1.0f : (p + EPSF);
        size_t o = ((size_t)bh * LL + gl) * HD + d;
        X[o] = __float2bfloat16(cv * p);    // mirror reference: C*P and B/D separate
        Y[o] = __float2bfloat16(bv / Dv);
        tv[l] = cv * bv;                    // diag partial (fp32 exact)
        if (gl >= 1) p *= a;                // advance to P[gl+1]
    }
    #pragma unroll
    for (int l = 0; l < CH; ++l) {
        float s = tv[l];
        #pragma unroll
        for (int off = 1; off < 64; off <<= 1) s += __shfl_xor(s, off);
        tv[l] = s;
    }
    if (d == 0) {
        float* dp = diag + (size_t)bh * LL + l0;
        #pragma unroll
        for (int q4 = 0; q4 < CH / 4; ++q4) {
            f32x4 v = {tv[4 * q4], tv[4 * q4 + 1], tv[4 * q4 + 2], tv[4 * q4 + 3]};
            *((f32x4*)dp + q4) = v;          // plain store: gemm reads this soon (L2)
        }
    }
}

// ------------- Kernel 4: MFMA bf16 GEMM  T = X Y^T (lower), diag, 0 ----------
// 128x128 tile, K=64 one-shot. LDS 2x16KB, 16B-chunk XOR swizzle (<=2-way, free).
// 4 waves, each 64x64 via 4x4 tiles of mfma_f32_16x16x32_bf16.
__global__ __launch_bounds__(256) void gemm_kernel(const __hip_bfloat16* __restrict__ X,
                                                   const __hip_bfloat16* __restrict__ Y,
                                                   const float* __restrict__ diag,
                                                   float* __restrict__ out) {
    int tj = blockIdx.x, ti = blockIdx.y, bh = blockIdx.z;
    size_t obase = (size_t)bh * LL * LL;
    int i0 = ti * 128, j0 = tj * 128;
    int t = threadIdx.x;

    if (tj > ti) {   // fully strict-upper tile: zero-fill only (uniform branch)
        f32x4 z = {0.f, 0.f, 0.f, 0.f};
        int col4 = t & 31, row0 = t >> 5;
        float* ob = out + obase + (size_t)i0 * LL + j0;
        #pragma unroll
        for (int r = 0; r < 16; ++r)
            nt_store4((f32x4*)(ob + (size_t)(row0 + 8 * r) * LL) + col4, z);
        return;
    }

    __shared__ short Xs[128 * 64];   // bf16 bits, row-major 64/row, swizzled chunks
    __shared__ short Ys[128 * 64];

    // ---- stage 128 rows x 64 bf16 per operand (16B/lane x 4 passes) ----
    {
        const f32x4* Xg4 = (const f32x4*)(X + ((size_t)bh * LL + i0) * HD);
        const f32x4* Yg4 = (const f32x4*)(Y + ((size_t)bh * LL + j0) * HD);
        int chunk = t & 7, r0 = t >> 3;    // chunk: 16B unit within row; r0: 0..31
        int sc = (chunk ^ (r0 & 7)) * 8;   // row&7 == r0&7 (rows step by 32)
        #pragma unroll
        for (int p = 0; p < 4; ++p) {
            int row = r0 + 32 * p;
            f32x4 vx = Xg4[row * 8 + chunk];
            f32x4 vy = Yg4[row * 8 + chunk];
            *(f32x4*)&Xs[row * 64 + sc] = vx;
            *(f32x4*)&Ys[row * 64 + sc] = vy;
        }
    }
    __syncthreads();

    // ---- compute: wave (wi,wj) owns 64x64; 4x4 tiles of 16x16, K=64 ----
    int lane = t & 63, wv = t >> 6;
    int wi = wv >> 1, wj = wv & 1;
    int l15 = lane & 15, q = lane >> 4;

    f32x4 acc[4][4] = {};
    #pragma unroll
    for (int kc = 0; kc < 2; ++kc) {
        bf16x8 af[4], bf[4];
        #pragma unroll
        for (int mt = 0; mt < 4; ++mt) {
            int row = 64 * wi + 16 * mt + l15;           // A[m][k]: m=lane&15
            int sc = ((4 * kc + q) ^ (row & 7)) * 8;     // k-chunk = 4*kc + quad
            af[mt] = *(const bf16x8*)&Xs[row * 64 + sc];
        }
        #pragma unroll
        for (int nt = 0; nt < 4; ++nt) {
            int row = 64 * wj + 16 * nt + l15;           // B[k][n]: n=lane&15
            int sc = ((4 * kc + q) ^ (row & 7)) * 8;
            bf[nt] = *(const bf16x8*)&Ys[row * 64 + sc];
        }
        #pragma unroll
        for (int mt = 0; mt < 4; ++mt)
            #pragma unroll
            for (int nt = 0; nt < 4; ++nt)
                acc[mt][nt] = __builtin_amdgcn_mfma_f32_16x16x32_bf16(
                    af[mt], bf[nt], acc[mt][nt], 0, 0, 0);
    }

    // ---- epilogue: C/D layout col=lane&15, row=quad*4+reg ----
    int i_base = i0 + 64 * wi, j_base = j0 + 64 * wj;
    if (tj < ti) {   // fully strict-lower: store everything
        #pragma unroll
        for (int mt = 0; mt < 4; ++mt)
            #pragma unroll
            for (int reg = 0; reg < 4; ++reg) {
                int gi = i_base + 16 * mt + 4 * q + reg;
                float* ob = out + obase + (size_t)gi * LL + j_base;
                #pragma unroll
                for (int nt = 0; nt < 4; ++nt)
                    nt_store(ob + 16 * nt + l15, acc[mt][nt][reg]);
            }
    } else {         // diagonal tile: mask j>i to 0, j==i to diag
        #pragma unroll
        for (int mt = 0; mt < 4; ++mt)
            #pragma unroll
            for (int reg = 0; reg < 4; ++reg) {
                int gi = i_base + 16 * mt + 4 * q + reg;
                float dv = diag[(size_t)bh * LL + gi];
                float* ob = out + obase + (size_t)gi * LL + j_base;
                #pragma unroll
                for (int nt = 0; nt < 4; ++nt) {
                    int gj = j_base + 16 * nt + l15;
                    float v = acc[mt][nt][reg];
                    nt_store(ob + 16 * nt + l15,
                             (gj < gi) ? v : ((gj == gi) ? dv : 0.f));
                }
            }
    }
}

extern "C" void kernel_launch(void* const* d_in, const int* in_sizes, int n_in,
                              void* d_out, int out_size, void* d_ws, size_t ws_size,
                              hipStream_t stream) {
    const float* Bg = (const float*)d_in[0];
    const float* Cg = (const float*)d_in[1];
    const float* S  = (const float*)d_in[2];
    float* out = (float*)d_out;

    char* ws = (char*)d_ws;
    size_t xy_bytes = (size_t)BHN * LL * HD * sizeof(__hip_bfloat16);  // 4 MB each
    __hip_bfloat16* X = (__hip_bfloat16*)(ws);
    __hip_bfloat16* Y = (__hip_bfloat16*)(ws + xy_bytes);
    float* diag = (float*)(ws + 2 * xy_bytes);
    float* U    = (float*)(ws + 2 * xy_bytes + (size_t)BHN * LL * sizeof(float));
    float* St   = (float*)(ws + 2 * xy_bytes + (size_t)BHN * LL * sizeof(float)
                              + (size_t)BHN * NC * HD * sizeof(float));

    chunkprod_kernel<<<dim3(NC, BHN), 64, 0, stream>>>(S, U);
    chunkscan_kernel<<<BHN, 1024, 0, stream>>>(U, St);
    apply_kernel<<<dim3(NC, BHN), 64, 0, stream>>>(Bg, Cg, S, St, X, Y, diag);
    gemm_kernel<<<dim3(16, 16, BHN), 256, 0, stream>>>(X, Y, diag, out);
}

// Round 7
// 291.879 us; speedup vs baseline: 1.1090x; 1.0260x over previous
//
#include <hip/hip_runtime.h>
#include <hip/hip_bf16.h>

#define LL   2048
#define DIM  512
#define HD   64
#define BHN  16      // batch * NH
#define NC   128     // chunks along L
#define CH   16      // chunk length = LL/NC
#define GC   8       // chunks per scan-group (NC / 16 groups)
#define EPSF 1e-8f

typedef __attribute__((ext_vector_type(8))) short bf16x8;   // 8 bf16 = 4 VGPRs
typedef __attribute__((ext_vector_type(4))) float f32x4;    // MFMA C/D + native 16B vector

__device__ __forceinline__ void nt_store4(f32x4* p, f32x4 v) {
    __builtin_nontemporal_store(v, p);
}

// ---------------- Kernel 1: per-chunk product of A (A_0 := 1) ----------------
__global__ __launch_bounds__(64) void chunkprod_kernel(const float* __restrict__ S,
                                                       float* __restrict__ U) {
    int c = blockIdx.x, bh = blockIdx.y;
    int b = bh >> 3, h = bh & 7;
    int d = threadIdx.x;
    int l0 = c * CH;
    size_t base = ((size_t)b * LL + l0) * DIM + h * HD + d;
    float p = 1.0f;
    #pragma unroll
    for (int l = 0; l < CH; ++l) {
        float a = S[base + (size_t)l * DIM];
        if (l0 + l >= 1) p *= a;   // position 0's A is replaced by 1
    }
    U[((size_t)bh * NC + c) * HD + d] = p;
}

// ------- Kernel 2: parallel exclusive scan of chunk products (per bh) --------
// 1024 threads: group g = t>>6 owns GC=8 chunks for channel d = t&63.
__global__ __launch_bounds__(1024) void chunkscan_kernel(const float* __restrict__ U,
                                                         float* __restrict__ St) {
    int bh = blockIdx.x;
    int t = threadIdx.x;
    int g = t >> 6, d = t & 63;
    int c0 = g * GC;
    float u[GC];
    float prod = 1.0f;
    #pragma unroll
    for (int k = 0; k < GC; ++k) {
        u[k] = U[((size_t)bh * NC + c0 + k) * HD + d];
        prod *= u[k];
    }
    __shared__ float Ls[16][64];
    Ls[g][d] = prod;
    __syncthreads();
    float run = 1.0f;
    for (int gg = 0; gg < g; ++gg) run *= Ls[gg][d];   // g uniform per wave
    #pragma unroll
    for (int k = 0; k < GC; ++k) {
        St[((size_t)bh * NC + c0 + k) * HD + d] = run;
        run *= u[k];
    }
}

// -- Kernel 3: rescan chunk: X = bf16(C*P), Y = bf16(B/D), diag = C.B (fused) -
__global__ __launch_bounds__(64) void apply_kernel(const float* __restrict__ Bg,
                                                   const float* __restrict__ Cg,
                                                   const float* __restrict__ S,
                                                   const float* __restrict__ St,
                                                   __hip_bfloat16* __restrict__ X,
                                                   __hip_bfloat16* __restrict__ Y,
                                                   float* __restrict__ diag) {
    int c = blockIdx.x, bh = blockIdx.y;
    int b = bh >> 3, h = bh & 7;
    int d = threadIdx.x;
    int l0 = c * CH;
    size_t gbase = ((size_t)b * LL + l0) * DIM + h * HD + d;
    float p = St[((size_t)bh * NC + c) * HD + d];   // P[l0] = prod_{k=1..l0-1} A_k
    float tv[CH];
    #pragma unroll
    for (int l = 0; l < CH; ++l) {
        int gl = l0 + l;
        size_t gi = gbase + (size_t)l * DIM;
        float a = S[gi], bv = Bg[gi], cv = Cg[gi];
        float Dv = (gl == 0) ? 1.0f : (p + EPSF);
        size_t o = ((size_t)bh * LL + gl) * HD + d;
        X[o] = __float2bfloat16(cv * p);    // mirror reference: C*P and B/D separate
        Y[o] = __float2bfloat16(bv / Dv);
        tv[l] = cv * bv;                    // diag partial (fp32 exact)
        if (gl >= 1) p *= a;                // advance to P[gl+1]
    }
    #pragma unroll
    for (int l = 0; l < CH; ++l) {
        float s = tv[l];
        #pragma unroll
        for (int off = 1; off < 64; off <<= 1) s += __shfl_xor(s, off);
        tv[l] = s;
    }
    if (d == 0) {
        float* dp = diag + (size_t)bh * LL + l0;
        #pragma unroll
        for (int q4 = 0; q4 < CH / 4; ++q4) {
            f32x4 v = {tv[4 * q4], tv[4 * q4 + 1], tv[4 * q4 + 2], tv[4 * q4 + 3]};
            *((f32x4*)dp + q4) = v;          // plain store: gemm reads this soon (L2)
        }
    }
}

// ------------- Kernel 4: MFMA bf16 GEMM  T = X Y^T (lower), diag, 0 ----------
// 128x128 tile, K=64 one-shot. LDS 2x16KB, 16B-chunk XOR swizzle (<=2-way, free).
// 4 waves, each 64x64 via 4x4 tiles of mfma_f32_16x16x32_bf16.
// Epilogue: wave-private LDS transpose (reusing Xs/Ys) -> dwordx4 stores.
__global__ __launch_bounds__(256) void gemm_kernel(const __hip_bfloat16* __restrict__ X,
                                                   const __hip_bfloat16* __restrict__ Y,
                                                   const float* __restrict__ diag,
                                                   float* __restrict__ out) {
    int tj = blockIdx.x, ti = blockIdx.y, bh = blockIdx.z;
    size_t obase = (size_t)bh * LL * LL;
    int i0 = ti * 128, j0 = tj * 128;
    int t = threadIdx.x;

    if (tj > ti) {   // fully strict-upper tile: zero-fill only (uniform branch)
        f32x4 z = {0.f, 0.f, 0.f, 0.f};
        int col4 = t & 31, row0 = t >> 5;
        float* ob = out + obase + (size_t)i0 * LL + j0;
        #pragma unroll
        for (int r = 0; r < 16; ++r)
            nt_store4((f32x4*)(ob + (size_t)(row0 + 8 * r) * LL) + col4, z);
        return;
    }

    __shared__ __align__(16) short Xs[128 * 64];   // bf16, row-major, swizzled chunks
    __shared__ __align__(16) short Ys[128 * 64];

    // ---- stage 128 rows x 64 bf16 per operand (16B/lane x 4 passes) ----
    {
        const f32x4* Xg4 = (const f32x4*)(X + ((size_t)bh * LL + i0) * HD);
        const f32x4* Yg4 = (const f32x4*)(Y + ((size_t)bh * LL + j0) * HD);
        int chunk = t & 7, r0 = t >> 3;    // chunk: 16B unit within row; r0: 0..31
        int sc = (chunk ^ (r0 & 7)) * 8;   // row&7 == r0&7 (rows step by 32)
        #pragma unroll
        for (int p = 0; p < 4; ++p) {
            int row = r0 + 32 * p;
            f32x4 vx = Xg4[row * 8 + chunk];
            f32x4 vy = Yg4[row * 8 + chunk];
            *(f32x4*)&Xs[row * 64 + sc] = vx;
            *(f32x4*)&Ys[row * 64 + sc] = vy;
        }
    }
    __syncthreads();

    // ---- compute: wave (wi,wj) owns 64x64; 4x4 tiles of 16x16, K=64 ----
    int lane = t & 63, wv = t >> 6;
    int wi = wv >> 1, wj = wv & 1;
    int l15 = lane & 15, q = lane >> 4;

    f32x4 acc[4][4] = {};
    #pragma unroll
    for (int kc = 0; kc < 2; ++kc) {
        bf16x8 af[4], bf[4];
        #pragma unroll
        for (int mt = 0; mt < 4; ++mt) {
            int row = 64 * wi + 16 * mt + l15;           // A[m][k]: m=lane&15
            int sc = ((4 * kc + q) ^ (row & 7)) * 8;     // k-chunk = 4*kc + quad
            af[mt] = *(const bf16x8*)&Xs[row * 64 + sc];
        }
        #pragma unroll
        for (int nt = 0; nt < 4; ++nt) {
            int row = 64 * wj + 16 * nt + l15;           // B[k][n]: n=lane&15
            int sc = ((4 * kc + q) ^ (row & 7)) * 8;
            bf[nt] = *(const bf16x8*)&Ys[row * 64 + sc];
        }
        #pragma unroll
        for (int mt = 0; mt < 4; ++mt)
            #pragma unroll
            for (int nt = 0; nt < 4; ++nt)
                acc[mt][nt] = __builtin_amdgcn_mfma_f32_16x16x32_bf16(
                    af[mt], bf[nt], acc[mt][nt], 0, 0, 0);
    }

    __syncthreads();   // Xs/Ys reads done in ALL waves before scratch reuse

    // ---- epilogue: mask in-register, transpose via wave-private LDS, x4 store
    // C/D layout: row = 16*mt + 4*q + reg, col = 16*nt + l15 (within 64x64).
    int i_base = i0 + 64 * wi, j_base = j0 + 64 * wj;
    bool is_diag = (tj == ti);
    float* tw = ((float*)Xs) + wv * 2048;   // 32 rows x 64 cols, 8 KB per wave

    #pragma unroll
    for (int hh = 0; hh < 2; ++hh) {        // halves: mt {0,1} then {2,3}
        #pragma unroll
        for (int mtl = 0; mtl < 2; ++mtl) {
            int mt = 2 * hh + mtl;
            #pragma unroll
            for (int reg = 0; reg < 4; ++reg) {
                int rl = 16 * mtl + 4 * q + reg;        // local row 0..31
                int gi = i_base + 32 * hh + rl;
                float dv = is_diag ? diag[(size_t)bh * LL + gi] : 0.f;
                #pragma unroll
                for (int nt = 0; nt < 4; ++nt) {
                    int c = 16 * nt + l15;
                    float v = acc[mt][nt][reg];
                    if (is_diag) {
                        int gj = j_base + c;
                        v = (gj < gi) ? v : ((gj == gi) ? dv : 0.f);
                    }
                    tw[rl * 64 + (c ^ (q << 4))] = v;   // swizzle: <=2-way, free
                }
            }
        }
        // read back row-major as float4 and store (4 rows x 16 chunks per pass)
        int rgrp = lane >> 4, chunk = lane & 15;
        #pragma unroll
        for (int pass = 0; pass < 8; ++pass) {
            int rl = 4 * pass + rgrp;
            int qr = (rl >> 2) & 3;                     // matches write-side q
            f32x4 v = *(f32x4*)&tw[rl * 64 + ((4 * chunk) ^ (qr << 4))];
            int gi = i_base + 32 * hh + rl;
            nt_store4((f32x4*)(out + obase + (size_t)gi * LL + j_base + 4 * chunk), v);
        }
    }
}

extern "C" void kernel_launch(void* const* d_in, const int* in_sizes, int n_in,
                              void* d_out, int out_size, void* d_ws, size_t ws_size,
                              hipStream_t stream) {
    const float* Bg = (const float*)d_in[0];
    const float* Cg = (const float*)d_in[1];
    const float* S  = (const float*)d_in[2];
    float* out = (float*)d_out;

    char* ws = (char*)d_ws;
    size_t xy_bytes = (size_t)BHN * LL * HD * sizeof(__hip_bfloat16);  // 4 MB each
    __hip_bfloat16* X = (__hip_bfloat16*)(ws);
    __hip_bfloat16* Y = (__hip_bfloat16*)(ws + xy_bytes);
    float* diag = (float*)(ws + 2 * xy_bytes);
    float* U    = (float*)(ws + 2 * xy_bytes + (size_t)BHN * LL * sizeof(float));
    float* St   = (float*)(ws + 2 * xy_bytes + (size_t)BHN * LL * sizeof(float)
                              + (size_t)BHN * NC * HD * sizeof(float));

    chunkprod_kernel<<<dim3(NC, BHN), 64, 0, stream>>>(S, U);
    chunkscan_kernel<<<BHN, 1024, 0, stream>>>(U, St);
    apply_kernel<<<dim3(NC, BHN), 64, 0, stream>>>(Bg, Cg, S, St, X, Y, diag);
    gemm_kernel<<<dim3(16, 16, BHN), 256, 0, stream>>>(X, Y, diag, out);
}